// Round 1
// baseline (164.659 us; speedup 1.0000x reference)
//
#include <hip/hip_runtime.h>
#include <math.h>

// Fused QWZ deformation + HS-distance kernel, v3.
// 32x32 output tile per 256-thread block; halo 33x33 deformed spinors in LDS.
// v3 changes vs v2 (theory: latency/occupancy-bound, VGPR-limited to ~20 waves/CU):
//  - Phase 1 is a 2-deep software pipeline (prefetch batch k+1 while deforming
//    batch k) instead of 5 batches fully staged -> ~14 floats live, not ~35.
//  - Phase 2 uses a rolling 2-row window (A,V <- H,D) instead of c0[5]/c1[5]
//    arrays -> 16 floats live, not 40.
//  - __launch_bounds__(256, 8) pins allocation at <=64 VGPRs -> 8 waves/SIMD
//    (100% occupancy; v2 was ~96 VGPRs -> 5 waves/SIMD = 62.5%).
//  - Tail batch fully predicated on l < NHALO (skips junk loads + trig).
#define TILE 32
#define HALO 33              // TILE + 1
#define NHALO (HALO * HALO)  // 1089

__global__ __launch_bounds__(256, 8) void qwz_deform_dirichlet_kernel(
    const float* __restrict__ theta,
    const float* __restrict__ phi,
    const float* __restrict__ psi,
    const float2* __restrict__ sre,   // state_re as [N] float2
    const float2* __restrict__ sim,   // state_im as [N] float2
    float* __restrict__ out,          // [3, mesh, mesh]
    int mesh)
{
    const int N = mesh * mesh;
    __shared__ float4 tile[NHALO];    // (re0, re1, im0, im1) per halo site

    const int bi = blockIdx.y * TILE;
    const int bj = blockIdx.x * TILE;
    const int tid = threadIdx.x;

    // ---- Phase 1: pipelined halo staging (load k+1 in flight over compute k) ----
    float th, ph, ps;
    float2 r, im;
    int n, l;

    // prologue: load batch 0 (all lanes valid: tid < 256 < NHALO)
    l = tid;
    {
        int trow = l / HALO;          // 0..7
        int tcol = l - trow * HALO;
        int gi = bi + trow; if (gi >= mesh) gi -= mesh;
        int gj = bj + tcol; if (gj >= mesh) gj -= mesh;
        n = gi * mesh + gj;
        int an = (n > 0) ? n - 1 : 0; // avoid theta[-1]
        th = theta[an];
        ph = phi[an];
        ps = psi[an];
        r  = sre[n];
        im = sim[n];
    }

#pragma unroll
    for (int k = 0; k < 5; ++k) {
        // rotate current batch into working regs
        const float thc = th, phc = ph, psc = ps;
        const float2 rc = r, imc = im;
        const int nc = n, lc = l;

        // prefetch batch k+1 (predicated; lanes past NHALO skip the loads)
        if (k < 4) {
            l = tid + (k + 1) * 256;
            if (l < NHALO) {
                int trow = l / HALO;
                int tcol = l - trow * HALO;
                int gi = bi + trow; if (gi >= mesh) gi -= mesh;
                int gj = bj + tcol; if (gj >= mesh) gj -= mesh;
                n = gi * mesh + gj;
                int an = (n > 0) ? n - 1 : 0;
                th = theta[an];
                ph = phi[an];
                ps = psi[an];
                r  = sre[n];
                im = sim[n];
            }
        }

        // deform current batch + LDS write
        if (lc < NHALO) {
            float st, ct, sp, cp, sq, cq;
            __sincosf(thc, &st, &ct);
            __sincosf(phc, &sp, &cp);
            __sincosf(psc, &sq, &cq);
            float a = ct * cp;   // su_re diag
            float b = st * cq;   // su_re off-diag
            float c = ct * sp;   // su_im diag
            float d = st * sq;   // su_im off-diag
            // d_re = su_re@s_re - su_im@s_im ; d_im = su_re@s_im + su_im@s_re
            float4 d4;
            d4.x = a * rc.x - b * rc.y - c * imc.x + d * imc.y;
            d4.y = b * rc.x + a * rc.y + d * imc.x + c * imc.y;
            d4.z = a * imc.x - b * imc.y + c * rc.x - d * rc.y;
            d4.w = b * imc.x + a * imc.y - d * rc.x - c * rc.y;
            if (nc == 0)              // site 0 keeps undeformed state
                d4 = make_float4(rc.x, rc.y, imc.x, imc.y);
            tile[lc] = d4;
        }
    }
    __syncthreads();

    // ---- Phase 2: 4 output rows per thread, rolling 2-row window ----
    const int trow = (tid >> 5) << 2;  // 0,4,...,28
    const int tcol = tid & 31;

    float4 A = tile[trow * HALO + tcol];
    float4 V = tile[trow * HALO + tcol + 1];

    int site = (bi + trow) * mesh + (bj + tcol);
    float* __restrict__ out_v = out;
    float* __restrict__ out_h = out + N;
    float* __restrict__ out_d = out + 2 * N;

#pragma unroll
    for (int k = 0; k < 4; ++k) {
        const float4 H = tile[(trow + k + 1) * HALO + tcol];
        const float4 D = tile[(trow + k + 1) * HALO + tcol + 1];

        float rr, ri, v, h, d;
        rr = A.x * V.x + A.y * V.y + A.z * V.z + A.w * V.w;
        ri = A.x * V.z + A.y * V.w - A.z * V.x - A.w * V.y;
        v = sqrtf(fabsf(1.0f - rr * rr - ri * ri));
        rr = A.x * H.x + A.y * H.y + A.z * H.z + A.w * H.w;
        ri = A.x * H.z + A.y * H.w - A.z * H.x - A.w * H.y;
        h = sqrtf(fabsf(1.0f - rr * rr - ri * ri));
        rr = A.x * D.x + A.y * D.y + A.z * D.z + A.w * D.w;
        ri = A.x * D.z + A.y * D.w - A.z * D.x - A.w * D.y;
        d = sqrtf(fabsf(1.0f - rr * rr - ri * ri));

        __builtin_nontemporal_store(v, out_v + site);
        __builtin_nontemporal_store(h, out_h + site);
        __builtin_nontemporal_store(d, out_d + site);

        A = H;                // row k+1 becomes current row
        V = D;
        site += mesh;
    }
}

extern "C" void kernel_launch(void* const* d_in, const int* in_sizes, int n_in,
                              void* d_out, int out_size, void* d_ws, size_t ws_size,
                              hipStream_t stream) {
    const float* theta = (const float*)d_in[0];
    const float* phi   = (const float*)d_in[1];
    const float* psi   = (const float*)d_in[2];
    const float2* sre  = (const float2*)d_in[3];
    const float2* sim  = (const float2*)d_in[4];
    float* out = (float*)d_out;

    int N = in_sizes[0] + 1;                       // theta has N-1 elements
    int mesh = (int)(sqrt((double)N) + 0.5);       // 2048

    dim3 grid(mesh / TILE, mesh / TILE);           // (64, 64)
    dim3 block(256);
    qwz_deform_dirichlet_kernel<<<grid, block, 0, stream>>>(
        theta, phi, psi, sre, sim, out, mesh);
}